// Round 10
// baseline (263.786 us; speedup 1.0000x reference)
//
#include <hip/hip_runtime.h>

typedef unsigned short u16;
typedef unsigned int   u32;
typedef __attribute__((ext_vector_type(8))) short short8;
typedef __attribute__((ext_vector_type(4))) float floatx4;

// ---------- helpers ----------
__device__ inline u16 f2bf(float x) {
  union { float f; unsigned u; } v; v.f = x;
  unsigned r = v.u + 0x7FFFu + ((v.u >> 16) & 1u);   // RNE
  return (u16)(r >> 16);
}
__device__ inline float bf2f(short s) {
  union { u32 u; float f; } v; v.u = ((u32)(u16)s) << 16; return v.f;
}
__device__ inline short8 ld8(const u16* p) {
  return *reinterpret_cast<const short8*>(p);
}
// async global->LDS DMA, 16B per lane; lds dest = wave-uniform base + lane*16
__device__ inline void async_ld16(const u16* g, u16* l) {
  unsigned loff = (unsigned)(unsigned long long)(void*)l;
  __builtin_amdgcn_global_load_lds(reinterpret_cast<const unsigned*>(g),
      reinterpret_cast<__attribute__((address_space(3))) unsigned*>(loff), 16, 0, 0);
}

// ---------- fused GroupNorm-1 + weight casts ----------
// blocks 0..255: GN over x (B,C,T) fp32 -> xn (B,T,C) bf16, single global read:
//   group (16ch x 2048t) staged as bf16 in exactly 64KB LDS; stats scratch
//   overlaps tile[0..63] (c=0,t<64), those pass-2 reads fall back to global.
// blocks 256..511: cast wq (786432 f) + wp (262144 f) fp32 -> bf16.
__global__ __launch_bounds__(1024) void gncast(const float* __restrict__ x,
                                               const float* __restrict__ gamma,
                                               const float* __restrict__ beta,
                                               u16* __restrict__ xn,
                                               const float* __restrict__ wq,
                                               u16* __restrict__ wqb,
                                               const float* __restrict__ wp,
                                               u16* __restrict__ wpb) {
  __shared__ u16 tile[16 * 2048];                 // 64KB exact
  float* stats = (float*)tile;                    // overlaps first 128B
  const int tid = threadIdx.x;
  if (blockIdx.x >= 256) {                        // ---- cast part ----
    int i = (blockIdx.x - 256) * 1024 + tid;      // float4 index
    const float* src; u16* dst; int j;
    if (i < 196608) { src = wq; dst = wqb; j = i; }
    else            { src = wp; dst = wpb; j = i - 196608; }
    float4 v = reinterpret_cast<const float4*>(src)[j];
    union { u16 u[4]; float2 f; } w;
    w.u[0] = f2bf(v.x); w.u[1] = f2bf(v.y); w.u[2] = f2bf(v.z); w.u[3] = f2bf(v.w);
    reinterpret_cast<float2*>(dst)[j] = w.f;
    return;
  }
  // ---- GN part ----
  int b = blockIdx.x >> 5, g = blockIdx.x & 31;
  const float* base = x + ((long)b * 512 + g * 16) * 2048;
  float s = 0.f, ss = 0.f;
  for (int i = tid; i < 8192; i += 1024) {        // pass 1: read + stage bf16
    float4 v = reinterpret_cast<const float4*>(base)[i];
    s  += v.x + v.y + v.z + v.w;
    ss += v.x * v.x + v.y * v.y + v.z * v.z + v.w * v.w;
    int c = i >> 9, t4 = (i & 511) * 4;
    union { u16 u[4]; float2 f; } w;
    w.u[0] = f2bf(v.x); w.u[1] = f2bf(v.y); w.u[2] = f2bf(v.z); w.u[3] = f2bf(v.w);
    *reinterpret_cast<float2*>(&tile[c * 2048 + t4]) = w.f;
  }
  #pragma unroll
  for (int d = 1; d < 64; d <<= 1) { s += __shfl_xor(s, d); ss += __shfl_xor(ss, d); }
  __syncthreads();                                 // tile writes done
  int wave = tid >> 6, lane = tid & 63;
  if (lane == 0) { stats[wave] = s; stats[wave + 16] = ss; }
  __syncthreads();
  s = 0.f; ss = 0.f;
  #pragma unroll
  for (int w = 0; w < 16; w++) { s += stats[w]; ss += stats[w + 16]; }
  float mean = s * (1.f / 32768.f);
  float var  = ss * (1.f / 32768.f) - mean * mean;
  float rstd = rsqrtf(var + 1e-5f);
  float ga[16], be[16];
  #pragma unroll
  for (int c = 0; c < 16; c++) {
    float gm = gamma[g * 16 + c];
    ga[c] = gm * rstd;
    be[c] = beta[g * 16 + c] - mean * rstd * gm;
  }
  u16* ob = xn + (long)b * 2048 * 512 + g * 16;
  #pragma unroll
  for (int tt = 0; tt < 2; tt++) {                 // pass 2: LDS -> xn
    int t = tid * 2 + tt;
    union { u16 u[8]; float4 f; } w0, w1;
    #pragma unroll
    for (int c = 0; c < 16; c++) {
      float f;
      if (c == 0 && t < 64) f = base[t];           // stats-overlap fallback
      else                  f = bf2f((short)tile[c * 2048 + t]);
      u16 o = f2bf(f * ga[c] + be[c]);
      if (c < 8) w0.u[c] = o; else w1.u[c - 8] = o;
    }
    u16* dst = ob + (long)t * 512;
    *reinterpret_cast<float4*>(dst)     = w0.f;
    *reinterpret_cast<float4*>(dst + 8) = w1.f;
  }
}

// ---------- GroupNorm 2: a (B,T,C) bf16 -> hn (B,T,C) bf16 ----------
__global__ __launch_bounds__(1024) void gn_tc(const u16* __restrict__ a,
                                              const float* __restrict__ gamma,
                                              const float* __restrict__ beta,
                                              u16* __restrict__ hn) {
  int b = blockIdx.x >> 5, g = blockIdx.x & 31;
  const u16* base = a + (long)b * 2048 * 512 + g * 16;
  float s = 0.f, ss = 0.f;
  for (int t = threadIdx.x; t < 2048; t += 1024) {
    const u16* p = base + (long)t * 512;
    short8 v0 = ld8(p), v1 = ld8(p + 8);
    #pragma unroll
    for (int j = 0; j < 8; j++) {
      float f0 = bf2f(v0[j]), f1 = bf2f(v1[j]);
      s += f0 + f1; ss += f0 * f0 + f1 * f1;
    }
  }
  #pragma unroll
  for (int d = 1; d < 64; d <<= 1) { s += __shfl_xor(s, d); ss += __shfl_xor(ss, d); }
  __shared__ float red[32];
  int wave = threadIdx.x >> 6, lane = threadIdx.x & 63;
  if (lane == 0) { red[wave] = s; red[wave + 16] = ss; }
  __syncthreads();
  s = 0.f; ss = 0.f;
  #pragma unroll
  for (int w = 0; w < 16; w++) { s += red[w]; ss += red[w + 16]; }
  float mean = s * (1.f / 32768.f);
  float var  = ss * (1.f / 32768.f) - mean * mean;
  float rstd = rsqrtf(var + 1e-5f);
  float ga[16], be[16];
  #pragma unroll
  for (int c = 0; c < 16; c++) {
    float gm = gamma[g * 16 + c];
    ga[c] = gm * rstd;
    be[c] = beta[g * 16 + c] - mean * rstd * gm;
  }
  u16* ob = hn + (long)b * 2048 * 512 + g * 16;
  for (int t = threadIdx.x; t < 2048; t += 1024) {
    const u16* p = base + (long)t * 512;
    short8 v0 = ld8(p), v1 = ld8(p + 8);
    union { u16 u[8]; float4 f; } w0, w1;
    #pragma unroll
    for (int c = 0; c < 8; c++)  w0.u[c] = f2bf(bf2f(v0[c]) * ga[c] + be[c]);
    #pragma unroll
    for (int c = 0; c < 8; c++)  w1.u[c] = f2bf(bf2f(v1[c]) * ga[c + 8] + be[c + 8]);
    u16* dst = ob + (long)t * 512;
    *reinterpret_cast<float4*>(dst)     = w0.f;
    *reinterpret_cast<float4*>(dst + 8) = w1.f;
  }
}

// ---------- unified TN GEMM: D[m][n] = sum_k A[m][k] * Bt[n][k] ----------
// Double-buffered async K-loop: one barrier/iter, prefetch k+1 during compute k.
// __launch_bounds__(256, 4): cap VGPR at 128 -> 4 blocks/CU. Measured neutral
// (round 9) but harmless; kept.
// QKV=1 adds a bijective XCD swizzle of the (x,y) plane (round 8, neutral,
// kept): remap w=(flat&7)*24+(flat>>3) groups each A-panel's 12 sharers on
// one XCD L2. gemm2 is NOT swizzled (default map already co-locates B-panel
// sharers).
template<int QKV>
__global__ __launch_bounds__(256, 4) void gemm_tn(
    const u16* __restrict__ A, long abst,
    const u16* __restrict__ Bt, long bbst,
    const float* __restrict__ bias,
    const float* __restrict__ resid, long rbst,
    void* __restrict__ outp, long obst,
    u16* __restrict__ vtp, int K) {
  __shared__ __align__(16) u16 As[2][128 * 32];
  __shared__ __align__(16) u16 Bs[2][128 * 32];
  const int tid = threadIdx.x;
  int bx = blockIdx.x, by = blockIdx.y;
  if (QKV) {
    int flat = by * gridDim.x + bx;
    int cpx = (gridDim.x * gridDim.y) >> 3;      // 192/8 = 24
    flat = (flat & 7) * cpx + (flat >> 3);
    bx = flat % gridDim.x; by = flat / gridDim.x;
  }
  const int m0 = by * 128, n0 = bx * 128;
  const int N = gridDim.x * 128;
  const long bz = blockIdx.z;
  const u16* Ab = A + bz * abst + (long)m0 * K;
  const u16* Bb = Bt + bz * bbst + (long)n0 * K;
  const int lane = tid & 63, wave = tid >> 6;
  const int wm = (wave & 1) * 64, wn = (wave >> 1) * 64;
  const int l15 = lane & 15, quad = lane >> 4;
  const u16* ag[2]; const u16* bg[2];
  const int ldso = wave * 512;
  #pragma unroll
  for (int half = 0; half < 2; half++) {
    int r = half * 64 + (tid >> 2);
    ag[half] = Ab + (long)r * K + (tid & 3) * 8;
    bg[half] = Bb + (long)r * K + (tid & 3) * 8;
  }

  floatx4 acc[4][4];
  #pragma unroll
  for (int i = 0; i < 4; i++)
    #pragma unroll
    for (int j = 0; j < 4; j++) acc[i][j] = (floatx4){0.f, 0.f, 0.f, 0.f};

  #pragma unroll
  for (int half = 0; half < 2; half++) {
    async_ld16(ag[half], &As[0][half * 2048 + ldso]);
    async_ld16(bg[half], &Bs[0][half * 2048 + ldso]);
  }
  const int nk = K >> 5;
  for (int ki = 0; ki < nk; ki++) {
    __syncthreads();
    if (ki + 1 < nk) {
      int k1 = (ki + 1) << 5, bsel = (ki + 1) & 1;
      #pragma unroll
      for (int half = 0; half < 2; half++) {
        async_ld16(ag[half] + k1, &As[bsel][half * 2048 + ldso]);
        async_ld16(bg[half] + k1, &Bs[bsel][half * 2048 + ldso]);
      }
    }
    const u16* as = As[ki & 1]; const u16* bs = Bs[ki & 1];
    short8 af[4], bfr[4];
    #pragma unroll
    for (int i = 0; i < 4; i++) af[i]  = ld8(&as[(wm + i * 16 + l15) * 32 + quad * 8]);
    #pragma unroll
    for (int i = 0; i < 4; i++) bfr[i] = ld8(&bs[(wn + i * 16 + l15) * 32 + quad * 8]);
    #pragma unroll
    for (int mi = 0; mi < 4; mi++)
      #pragma unroll
      for (int ni = 0; ni < 4; ni++)
        acc[mi][ni] = __builtin_amdgcn_mfma_f32_16x16x32_bf16(af[mi], bfr[ni], acc[mi][ni], 0, 0, 0);
  }

  if (QKV) {
    u16* D  = (u16*)outp + bz * obst;
    u16* VT = vtp + bz * (8L * 64 * 2048);
    #pragma unroll
    for (int ni = 0; ni < 4; ni++) {
      int nb = n0 + wn + ni * 16;
      int region = (nb >> 6) % 3;              // 0=q, 1=k, 2=v
      int n = nb + l15;
      float bn = bias[n];
      if (region == 2) {
        int hh = n / 192, c = (n % 192) - 128;
        u16* vrow = VT + ((long)hh * 64 + c) * 2048 + m0 + wm;
        #pragma unroll
        for (int mi = 0; mi < 4; mi++) {
          union { u16 u[4]; float2 f; } pk;
          #pragma unroll
          for (int r = 0; r < 4; r++) pk.u[r] = f2bf(acc[mi][ni][r] + bn);
          *reinterpret_cast<float2*>(vrow + mi * 16 + quad * 4) = pk.f;
        }
      } else {
        float sc = (region == 0) ? 0.180336880f : 1.f;   // 0.125 * log2(e)
        #pragma unroll
        for (int mi = 0; mi < 4; mi++)
          #pragma unroll
          for (int r = 0; r < 4; r++) {
            int m = m0 + wm + mi * 16 + quad * 4 + r;
            D[(long)m * 1536 + n] = f2bf((acc[mi][ni][r] + bn) * sc);
          }
      }
    }
  } else {
    float* D = (float*)outp + bz * obst;
    const float* R = resid + bz * rbst;
    #pragma unroll
    for (int mi = 0; mi < 4; mi++)
      #pragma unroll
      for (int r = 0; r < 4; r++) {
        int m = m0 + wm + mi * 16 + quad * 4 + r;
        float bm = bias[m];
        #pragma unroll
        for (int ni = 0; ni < 4; ni++) {
          int n = n0 + wn + ni * 16 + l15;
          long idx = (long)m * N + n;
          D[idx] = acc[mi][ni][r] + bm + R[idx];
        }
      }
  }
}

// ---------- flash attention (KVBLK=128 as 2x 64x64 sub-tiles; register P) ----------
// Compute body is the VERIFIED round-3 kernel verbatim; only the staging loop
// changed: each barrier now publishes TWO 64x64 K/V sub-tiles (KVBLK=128),
// halving barrier/drain count 32 -> 16 and doubling DMA latency cover. All
// fragment reads, swizzle, pack, MFMA sequences are byte-identical per
// sub-tile. LDS 64KB -> still 2 blocks/CU (128KB <= 160KB).
// qkv: (B,T,1536) bf16, Q pre-scaled by 0.125*log2e; vt: (B,NH,64,T) bf16.
// No-max softmax (bounded scores), l via ones-MFMA (numerator/denominator
// share bf16 truncation -> bias cancels in O/l; round-6 lesson).
// P never touches LDS: QK^T output sacc[tki][tqi] holds, per lane,
//   P[tq=tqi*16+l15][tk=16*tki+4*quad+r].  The PV B-fragment needs
//   P[tq=tqi*16+l15][tk=32*ks+8*quad+j].  Fixed-l15 cross-quad redistribution
//   via permlane32_swap + permlane16_swap (round-1 derivation).
// Grid 512 1D: bh = id&63, tqb = id>>6 (K/V L2 locality; perf-only).
__global__ __launch_bounds__(512, 4) void attn(const u16* __restrict__ qkv,
                                               const u16* __restrict__ vt,
                                               u16* __restrict__ aout) {
  __shared__ __align__(16) u16 Ks[2][2][64 * 64];   // [buf][half] 4x8KB
  __shared__ __align__(16) u16 Vs[2][2][64 * 64];   // [buf][half] 4x8KB
  const int tid = threadIdx.x, lane = tid & 63, wave = tid >> 6;
  const int l15 = lane & 15, quad = lane >> 4;
  const int sw = l15 & 7;                        // row-swizzle key
  const int bh = blockIdx.x & 63;
  const int b = bh >> 3, h = bh & 7;
  const int t0 = (blockIdx.x >> 6) * 256;
  const u16* qbase = qkv + (long)b * 2048 * 1536 + h * 192;
  const u16* vbase = vt + (long)(b * 8 + h) * 64 * 2048;

  // Q fragments straight from global (A-layout: 16B/lane); wave owns 32 rows
  short8 qf[2][2];
  #pragma unroll
  for (int tqi = 0; tqi < 2; tqi++)
    #pragma unroll
    for (int ks = 0; ks < 2; ks++)
      qf[tqi][ks] = ld8(qbase + (long)(t0 + wave * 32 + tqi * 16 + l15) * 1536 + ks * 32 + quad * 8);

  // ones A-fragment for l-sum MFMA (bf16 1.0 = 0x3F80)
  short8 ones;
  #pragma unroll
  for (int j = 0; j < 8; j++) ones[j] = (short)0x3F80;

  // staging: 512 threads cover the 512 16B chunks of each 64x64 sub-tile.
  // thread covers phys chunk p=tid, reads logical chunk c = (p&7)^(row&7)
  const int prow = tid >> 3, pc = (tid & 7) ^ (prow & 7);
  const u16* kg = qbase + (long)prow * 1536 + 64 + pc * 8;
  const u16* vg = vbase + (long)prow * 2048 + pc * 8;
  const int ldso = wave * 512;                   // wave-uniform base (u16 units)
  #pragma unroll
  for (int hf = 0; hf < 2; hf++) {               // stage tile 0 (both halves)
    async_ld16(kg + (long)(hf * 64) * 1536, &Ks[0][hf][ldso]);
    async_ld16(vg + hf * 64,               &Vs[0][hf][ldso]);
  }

  floatx4 accO[4][2];   // [ci][tqi]: row=c, col=tq
  floatx4 lacc[2];      // [tqi]
  #pragma unroll
  for (int ci = 0; ci < 4; ci++)
    #pragma unroll
    for (int tqi = 0; tqi < 2; tqi++) accO[ci][tqi] = (floatx4){0.f, 0.f, 0.f, 0.f};
  #pragma unroll
  for (int tqi = 0; tqi < 2; tqi++) lacc[tqi] = (floatx4){0.f, 0.f, 0.f, 0.f};

  for (int it = 0; it < 16; it++) {              // 16 x 128-row K/V tiles
    __syncthreads();                   // publishes tile it; frees buffer it^1
    if (it < 15) {                     // prefetch tile it+1 (both halves)
      int s1 = (it + 1) * 128;
      #pragma unroll
      for (int hf = 0; hf < 2; hf++) {
        async_ld16(kg + (long)(s1 + hf * 64) * 1536, &Ks[(it & 1) ^ 1][hf][ldso]);
        async_ld16(vg + s1 + hf * 64,               &Vs[(it & 1) ^ 1][hf][ldso]);
      }
    }

    #pragma unroll
    for (int hf = 0; hf < 2; hf++) {             // two 64x64 sub-tiles/barrier
      const u16* kb = Ks[it & 1][hf];
      const u16* vb = Vs[it & 1][hf];

      // S^T[tk][tq] = sum_c K[tk][c] * Q[tq][c]
      floatx4 sacc[4][2];   // [tki][tqi]
      #pragma unroll
      for (int i = 0; i < 4; i++)
        #pragma unroll
        for (int j = 0; j < 2; j++) sacc[i][j] = (floatx4){0.f, 0.f, 0.f, 0.f};
      #pragma unroll
      for (int ks = 0; ks < 2; ks++) {
        short8 kf[4];
        #pragma unroll
        for (int tki = 0; tki < 4; tki++)
          kf[tki] = ld8(&kb[((tki * 16 + l15) << 6) + (((ks * 4 + quad) ^ sw) << 3)]);
        #pragma unroll
        for (int tki = 0; tki < 4; tki++)
          #pragma unroll
          for (int tqi = 0; tqi < 2; tqi++)
            sacc[tki][tqi] = __builtin_amdgcn_mfma_f32_16x16x32_bf16(kf[tki], qf[tqi][ks], sacc[tki][tqi], 0, 0, 0);
      }

      // p = exp2(s) in place (no max-sub; bounded domain)
      #pragma unroll
      for (int tki = 0; tki < 4; tki++)
        #pragma unroll
        for (int tqi = 0; tqi < 2; tqi++)
          #pragma unroll
          for (int r = 0; r < 4; r++)
            sacc[tki][tqi][r] = __builtin_amdgcn_exp2f(sacc[tki][tqi][r]);

      // O^T[c][tq] += sum_tk V^T[c][tk] * P[tq][tk]; l[tq] += sum_tk P
      #pragma unroll
      for (int ks = 0; ks < 2; ks++) {
        short8 vf[4], pf[2];
        #pragma unroll
        for (int ci = 0; ci < 4; ci++)
          vf[ci] = ld8(&vb[((ci * 16 + l15) << 6) + (((ks * 4 + quad) ^ sw) << 3)]);
        #pragma unroll
        for (int tqi = 0; tqi < 2; tqi++) {
          // pack to bf16 words: lo = even-tk, hi = odd-tk (truncation, as before)
          u32 a0 = __builtin_amdgcn_perm(__float_as_uint(sacc[2 * ks][tqi][1]),
                                         __float_as_uint(sacc[2 * ks][tqi][0]), 0x07060302);
          u32 a1 = __builtin_amdgcn_perm(__float_as_uint(sacc[2 * ks][tqi][3]),
                                         __float_as_uint(sacc[2 * ks][tqi][2]), 0x07060302);
          u32 b0 = __builtin_amdgcn_perm(__float_as_uint(sacc[2 * ks + 1][tqi][1]),
                                         __float_as_uint(sacc[2 * ks + 1][tqi][0]), 0x07060302);
          u32 b1 = __builtin_amdgcn_perm(__float_as_uint(sacc[2 * ks + 1][tqi][3]),
                                         __float_as_uint(sacc[2 * ks + 1][tqi][2]), 0x07060302);
          auto u0 = __builtin_amdgcn_permlane32_swap(a0, b0, false, false);
          auto v0 = __builtin_amdgcn_permlane16_swap(u0[0], u0[1], false, false); // w0, w2
          auto u1 = __builtin_amdgcn_permlane32_swap(a1, b1, false, false);
          auto v1 = __builtin_amdgcn_permlane16_swap(u1[0], u1[1], false, false); // w1, w3
          union { u32 w[4]; short8 s8; } pw;
          pw.w[0] = v0[0]; pw.w[1] = v1[0]; pw.w[2] = v0[1]; pw.w[3] = v1[1];
          pf[tqi] = pw.s8;
        }
        #pragma unroll
        for (int tqi = 0; tqi < 2; tqi++)
          lacc[tqi] = __builtin_amdgcn_mfma_f32_16x16x32_bf16(ones, pf[tqi], lacc[tqi], 0, 0, 0);
        #pragma unroll
        for (int ci = 0; ci < 4; ci++)
          #pragma unroll
          for (int tqi = 0; tqi < 2; tqi++)
            accO[ci][tqi] = __builtin_amdgcn_mfma_f32_16x16x32_bf16(vf[ci], pf[tqi], accO[ci][tqi], 0, 0, 0);
      }
    }
  }

  // epilogue: normalize, write a (B,T,C) bf16; lane holds 4 consecutive c
  u16* ob = aout + ((long)b * 2048 + t0 + wave * 32) * 512 + h * 64;
  #pragma unroll
  for (int tqi = 0; tqi < 2; tqi++) {
    float invl = 1.f / lacc[tqi][0];
    #pragma unroll
    for (int ci = 0; ci < 4; ci++) {
      union { u16 u[4]; float2 f; } pk;
      #pragma unroll
      for (int r = 0; r < 4; r++) pk.u[r] = f2bf(accO[ci][tqi][r] * invl);
      *reinterpret_cast<float2*>(ob + (long)(tqi * 16 + l15) * 512 + ci * 16 + quad * 4) = pk.f;
    }
  }
}

// ---------- launch ----------
extern "C" void kernel_launch(void* const* d_in, const int* in_sizes, int n_in,
                              void* d_out, int out_size, void* d_ws, size_t ws_size,
                              hipStream_t stream) {
  const float* x   = (const float*)d_in[0];
  const float* g1  = (const float*)d_in[1];
  const float* be1 = (const float*)d_in[2];
  const float* wq  = (const float*)d_in[3];
  const float* bq  = (const float*)d_in[4];
  const float* g2  = (const float*)d_in[5];
  const float* be2 = (const float*)d_in[6];
  const float* wp  = (const float*)d_in[7];
  const float* bp  = (const float*)d_in[8];

  char* ws = (char*)d_ws;
  u16*   xn   = (u16*)ws;                        // 16.8 MB, dead after gemm1
  u16*   a    = (u16*)ws;                        // bf16 attn out, alias xn (disjoint lifetime)
  u16*   qkvb = (u16*)(ws + 33554432);           // 50.3 MB (q/k live, v-holes unused)
  u16*   hn   = (u16*)(ws + 83886080);           // 16.8 MB, gn2 -> gemm2
  u16*   vtb  = hn;                              // alias: Vt lifetime gemm1 -> attn
  u16*   wqb  = (u16*)(ws + 100663296);          // 1.6 MB
  u16*   wpb  = (u16*)(ws + 102236160);          // 0.5 MB

  gncast<<<512, 1024, 0, stream>>>(x, g1, be1, xn, wq, wqb, wp, wpb);
  // qkv[b][t][o] = sum_c xn[b][t][c] * Wq[o][c] + bq[o]  (+ q-scale, v->Vt)
  gemm_tn<1><<<dim3(12, 16, 8), 256, 0, stream>>>(
      xn, (long)2048 * 512, wqb, 0, bq, nullptr, 0, qkvb, (long)2048 * 1536, vtb, 512);
  attn<<<512, 512, 0, stream>>>(qkvb, vtb, a);
  gn_tc<<<256, 1024, 0, stream>>>(a, g2, be2, hn);
  // out[b][o][t] = x[b][o][t] + bp[o] + sum_c Wp[o][c] * hn[b][t][c]
  gemm_tn<0><<<dim3(16, 4, 8), 256, 0, stream>>>(
      wpb, 0, hn, (long)2048 * 512, bp, x, (long)512 * 2048, d_out, (long)512 * 2048, nullptr, 512);
}

// Round 11
// 260.024 us; speedup vs baseline: 1.0145x; 1.0145x over previous
//
#include <hip/hip_runtime.h>

typedef unsigned short u16;
typedef unsigned int   u32;
typedef __attribute__((ext_vector_type(8))) short short8;
typedef __attribute__((ext_vector_type(4))) float floatx4;

// ---------- helpers ----------
__device__ inline u16 f2bf(float x) {
  union { float f; unsigned u; } v; v.f = x;
  unsigned r = v.u + 0x7FFFu + ((v.u >> 16) & 1u);   // RNE
  return (u16)(r >> 16);
}
__device__ inline float bf2f(short s) {
  union { u32 u; float f; } v; v.u = ((u32)(u16)s) << 16; return v.f;
}
__device__ inline short8 ld8(const u16* p) {
  return *reinterpret_cast<const short8*>(p);
}
// async global->LDS DMA, 16B per lane; lds dest = wave-uniform base + lane*16
__device__ inline void async_ld16(const u16* g, u16* l) {
  unsigned loff = (unsigned)(unsigned long long)(void*)l;
  __builtin_amdgcn_global_load_lds(reinterpret_cast<const unsigned*>(g),
      reinterpret_cast<__attribute__((address_space(3))) unsigned*>(loff), 16, 0, 0);
}

// ---------- fused GroupNorm-1 + weight casts ----------
// blocks 0..255: GN over x (B,C,T) fp32 -> xn (B,T,C) bf16, single global read:
//   group (16ch x 2048t) staged as bf16 in exactly 64KB LDS; stats scratch
//   overlaps tile[0..63] (c=0,t<64), those pass-2 reads fall back to global.
// blocks 256..511: cast wq (786432 f) + wp (262144 f) fp32 -> bf16.
__global__ __launch_bounds__(1024) void gncast(const float* __restrict__ x,
                                               const float* __restrict__ gamma,
                                               const float* __restrict__ beta,
                                               u16* __restrict__ xn,
                                               const float* __restrict__ wq,
                                               u16* __restrict__ wqb,
                                               const float* __restrict__ wp,
                                               u16* __restrict__ wpb) {
  __shared__ u16 tile[16 * 2048];                 // 64KB exact
  float* stats = (float*)tile;                    // overlaps first 128B
  const int tid = threadIdx.x;
  if (blockIdx.x >= 256) {                        // ---- cast part ----
    int i = (blockIdx.x - 256) * 1024 + tid;      // float4 index
    const float* src; u16* dst; int j;
    if (i < 196608) { src = wq; dst = wqb; j = i; }
    else            { src = wp; dst = wpb; j = i - 196608; }
    float4 v = reinterpret_cast<const float4*>(src)[j];
    union { u16 u[4]; float2 f; } w;
    w.u[0] = f2bf(v.x); w.u[1] = f2bf(v.y); w.u[2] = f2bf(v.z); w.u[3] = f2bf(v.w);
    reinterpret_cast<float2*>(dst)[j] = w.f;
    return;
  }
  // ---- GN part ----
  int b = blockIdx.x >> 5, g = blockIdx.x & 31;
  const float* base = x + ((long)b * 512 + g * 16) * 2048;
  float s = 0.f, ss = 0.f;
  for (int i = tid; i < 8192; i += 1024) {        // pass 1: read + stage bf16
    float4 v = reinterpret_cast<const float4*>(base)[i];
    s  += v.x + v.y + v.z + v.w;
    ss += v.x * v.x + v.y * v.y + v.z * v.z + v.w * v.w;
    int c = i >> 9, t4 = (i & 511) * 4;
    union { u16 u[4]; float2 f; } w;
    w.u[0] = f2bf(v.x); w.u[1] = f2bf(v.y); w.u[2] = f2bf(v.z); w.u[3] = f2bf(v.w);
    *reinterpret_cast<float2*>(&tile[c * 2048 + t4]) = w.f;
  }
  #pragma unroll
  for (int d = 1; d < 64; d <<= 1) { s += __shfl_xor(s, d); ss += __shfl_xor(ss, d); }
  __syncthreads();                                 // tile writes done
  int wave = tid >> 6, lane = tid & 63;
  if (lane == 0) { stats[wave] = s; stats[wave + 16] = ss; }
  __syncthreads();
  s = 0.f; ss = 0.f;
  #pragma unroll
  for (int w = 0; w < 16; w++) { s += stats[w]; ss += stats[w + 16]; }
  float mean = s * (1.f / 32768.f);
  float var  = ss * (1.f / 32768.f) - mean * mean;
  float rstd = rsqrtf(var + 1e-5f);
  float ga[16], be[16];
  #pragma unroll
  for (int c = 0; c < 16; c++) {
    float gm = gamma[g * 16 + c];
    ga[c] = gm * rstd;
    be[c] = beta[g * 16 + c] - mean * rstd * gm;
  }
  u16* ob = xn + (long)b * 2048 * 512 + g * 16;
  #pragma unroll
  for (int tt = 0; tt < 2; tt++) {                 // pass 2: LDS -> xn
    int t = tid * 2 + tt;
    union { u16 u[8]; float4 f; } w0, w1;
    #pragma unroll
    for (int c = 0; c < 16; c++) {
      float f;
      if (c == 0 && t < 64) f = base[t];           // stats-overlap fallback
      else                  f = bf2f((short)tile[c * 2048 + t]);
      u16 o = f2bf(f * ga[c] + be[c]);
      if (c < 8) w0.u[c] = o; else w1.u[c - 8] = o;
    }
    u16* dst = ob + (long)t * 512;
    *reinterpret_cast<float4*>(dst)     = w0.f;
    *reinterpret_cast<float4*>(dst + 8) = w1.f;
  }
}

// ---------- GroupNorm 2: a (B,T,C) bf16 -> hn (B,T,C) bf16 ----------
__global__ __launch_bounds__(1024) void gn_tc(const u16* __restrict__ a,
                                              const float* __restrict__ gamma,
                                              const float* __restrict__ beta,
                                              u16* __restrict__ hn) {
  int b = blockIdx.x >> 5, g = blockIdx.x & 31;
  const u16* base = a + (long)b * 2048 * 512 + g * 16;
  float s = 0.f, ss = 0.f;
  for (int t = threadIdx.x; t < 2048; t += 1024) {
    const u16* p = base + (long)t * 512;
    short8 v0 = ld8(p), v1 = ld8(p + 8);
    #pragma unroll
    for (int j = 0; j < 8; j++) {
      float f0 = bf2f(v0[j]), f1 = bf2f(v1[j]);
      s += f0 + f1; ss += f0 * f0 + f1 * f1;
    }
  }
  #pragma unroll
  for (int d = 1; d < 64; d <<= 1) { s += __shfl_xor(s, d); ss += __shfl_xor(ss, d); }
  __shared__ float red[32];
  int wave = threadIdx.x >> 6, lane = threadIdx.x & 63;
  if (lane == 0) { red[wave] = s; red[wave + 16] = ss; }
  __syncthreads();
  s = 0.f; ss = 0.f;
  #pragma unroll
  for (int w = 0; w < 16; w++) { s += red[w]; ss += red[w + 16]; }
  float mean = s * (1.f / 32768.f);
  float var  = ss * (1.f / 32768.f) - mean * mean;
  float rstd = rsqrtf(var + 1e-5f);
  float ga[16], be[16];
  #pragma unroll
  for (int c = 0; c < 16; c++) {
    float gm = gamma[g * 16 + c];
    ga[c] = gm * rstd;
    be[c] = beta[g * 16 + c] - mean * rstd * gm;
  }
  u16* ob = hn + (long)b * 2048 * 512 + g * 16;
  for (int t = threadIdx.x; t < 2048; t += 1024) {
    const u16* p = base + (long)t * 512;
    short8 v0 = ld8(p), v1 = ld8(p + 8);
    union { u16 u[8]; float4 f; } w0, w1;
    #pragma unroll
    for (int c = 0; c < 8; c++)  w0.u[c] = f2bf(bf2f(v0[c]) * ga[c] + be[c]);
    #pragma unroll
    for (int c = 0; c < 8; c++)  w1.u[c] = f2bf(bf2f(v1[c]) * ga[c + 8] + be[c + 8]);
    u16* dst = ob + (long)t * 512;
    *reinterpret_cast<float4*>(dst)     = w0.f;
    *reinterpret_cast<float4*>(dst + 8) = w1.f;
  }
}

// ---------- unified TN GEMM: D[m][n] = sum_k A[m][k] * Bt[n][k] ----------
// Double-buffered async K-loop: one barrier/iter, prefetch k+1 during compute k.
// __launch_bounds__(256, 4): cap VGPR at 128 -> 4 blocks/CU. Measured neutral
// (round 9) but harmless; kept.
// QKV=1 adds a bijective XCD swizzle of the (x,y) plane (round 8, neutral,
// kept): remap w=(flat&7)*24+(flat>>3) groups each A-panel's 12 sharers on
// one XCD L2. gemm2 is NOT swizzled (default map already co-locates B-panel
// sharers).
template<int QKV>
__global__ __launch_bounds__(256, 4) void gemm_tn(
    const u16* __restrict__ A, long abst,
    const u16* __restrict__ Bt, long bbst,
    const float* __restrict__ bias,
    const float* __restrict__ resid, long rbst,
    void* __restrict__ outp, long obst,
    u16* __restrict__ vtp, int K) {
  __shared__ __align__(16) u16 As[2][128 * 32];
  __shared__ __align__(16) u16 Bs[2][128 * 32];
  const int tid = threadIdx.x;
  int bx = blockIdx.x, by = blockIdx.y;
  if (QKV) {
    int flat = by * gridDim.x + bx;
    int cpx = (gridDim.x * gridDim.y) >> 3;      // 192/8 = 24
    flat = (flat & 7) * cpx + (flat >> 3);
    bx = flat % gridDim.x; by = flat / gridDim.x;
  }
  const int m0 = by * 128, n0 = bx * 128;
  const int N = gridDim.x * 128;
  const long bz = blockIdx.z;
  const u16* Ab = A + bz * abst + (long)m0 * K;
  const u16* Bb = Bt + bz * bbst + (long)n0 * K;
  const int lane = tid & 63, wave = tid >> 6;
  const int wm = (wave & 1) * 64, wn = (wave >> 1) * 64;
  const int l15 = lane & 15, quad = lane >> 4;
  const u16* ag[2]; const u16* bg[2];
  const int ldso = wave * 512;
  #pragma unroll
  for (int half = 0; half < 2; half++) {
    int r = half * 64 + (tid >> 2);
    ag[half] = Ab + (long)r * K + (tid & 3) * 8;
    bg[half] = Bb + (long)r * K + (tid & 3) * 8;
  }

  floatx4 acc[4][4];
  #pragma unroll
  for (int i = 0; i < 4; i++)
    #pragma unroll
    for (int j = 0; j < 4; j++) acc[i][j] = (floatx4){0.f, 0.f, 0.f, 0.f};

  #pragma unroll
  for (int half = 0; half < 2; half++) {
    async_ld16(ag[half], &As[0][half * 2048 + ldso]);
    async_ld16(bg[half], &Bs[0][half * 2048 + ldso]);
  }
  const int nk = K >> 5;
  for (int ki = 0; ki < nk; ki++) {
    __syncthreads();
    if (ki + 1 < nk) {
      int k1 = (ki + 1) << 5, bsel = (ki + 1) & 1;
      #pragma unroll
      for (int half = 0; half < 2; half++) {
        async_ld16(ag[half] + k1, &As[bsel][half * 2048 + ldso]);
        async_ld16(bg[half] + k1, &Bs[bsel][half * 2048 + ldso]);
      }
    }
    const u16* as = As[ki & 1]; const u16* bs = Bs[ki & 1];
    short8 af[4], bfr[4];
    #pragma unroll
    for (int i = 0; i < 4; i++) af[i]  = ld8(&as[(wm + i * 16 + l15) * 32 + quad * 8]);
    #pragma unroll
    for (int i = 0; i < 4; i++) bfr[i] = ld8(&bs[(wn + i * 16 + l15) * 32 + quad * 8]);
    #pragma unroll
    for (int mi = 0; mi < 4; mi++)
      #pragma unroll
      for (int ni = 0; ni < 4; ni++)
        acc[mi][ni] = __builtin_amdgcn_mfma_f32_16x16x32_bf16(af[mi], bfr[ni], acc[mi][ni], 0, 0, 0);
  }

  if (QKV) {
    u16* D  = (u16*)outp + bz * obst;
    u16* VT = vtp + bz * (8L * 64 * 2048);
    #pragma unroll
    for (int ni = 0; ni < 4; ni++) {
      int nb = n0 + wn + ni * 16;
      int region = (nb >> 6) % 3;              // 0=q, 1=k, 2=v
      int n = nb + l15;
      float bn = bias[n];
      if (region == 2) {
        int hh = n / 192, c = (n % 192) - 128;
        u16* vrow = VT + ((long)hh * 64 + c) * 2048 + m0 + wm;
        #pragma unroll
        for (int mi = 0; mi < 4; mi++) {
          union { u16 u[4]; float2 f; } pk;
          #pragma unroll
          for (int r = 0; r < 4; r++) pk.u[r] = f2bf(acc[mi][ni][r] + bn);
          *reinterpret_cast<float2*>(vrow + mi * 16 + quad * 4) = pk.f;
        }
      } else {
        float sc = (region == 0) ? 0.180336880f : 1.f;   // 0.125 * log2(e)
        #pragma unroll
        for (int mi = 0; mi < 4; mi++)
          #pragma unroll
          for (int r = 0; r < 4; r++) {
            int m = m0 + wm + mi * 16 + quad * 4 + r;
            D[(long)m * 1536 + n] = f2bf((acc[mi][ni][r] + bn) * sc);
          }
      }
    }
  } else {
    float* D = (float*)outp + bz * obst;
    const float* R = resid + bz * rbst;
    #pragma unroll
    for (int mi = 0; mi < 4; mi++)
      #pragma unroll
      for (int r = 0; r < 4; r++) {
        int m = m0 + wm + mi * 16 + quad * 4 + r;
        float bm = bias[m];
        #pragma unroll
        for (int ni = 0; ni < 4; ni++) {
          int n = n0 + wn + ni * 16 + l15;
          long idx = (long)m * N + n;
          D[idx] = acc[mi][ni][r] + bm + R[idx];
        }
      }
  }
}

// ---------- flash attention (8 waves x 32 tq rows; register-resident P) ----------
// VERIFIED round-3 kernel, final. Issue-port-saturated: MfmaUtil+VALUBusy ~93%
// with neither pipe >55%, invariant under occupancy 2x (r3), no-LDS (r4, 3.3x
// worse), deferred-PV (r5, null), KVBLK=128 (r10, -5.8%: L2 thrash > barrier
// saving). Demand-reduction (32x32) failed correctness twice; retired.
// qkv: (B,T,1536) bf16, Q pre-scaled by 0.125*log2e; vt: (B,NH,64,T) bf16.
// No-max softmax (bounded scores), l via ones-MFMA (same truncated pf as PV:
// truncation bias cancels in O/l).
// P never touches LDS: QK^T output sacc[tki][tqi] holds, per lane,
//   P[tq=tqi*16+l15][tk=16*tki+4*quad+r].  The PV B-fragment needs
//   P[tq=tqi*16+l15][tk=32*ks+8*quad+j].  Fixed-l15 cross-quad redistribution
//   via permlane32_swap + permlane16_swap (round-1 derivation).
// Grid 512 1D: bh = id&63, tqb = id>>6 (K/V L2 locality; perf-only).
__global__ __launch_bounds__(512, 4) void attn(const u16* __restrict__ qkv,
                                               const u16* __restrict__ vt,
                                               u16* __restrict__ aout) {
  __shared__ __align__(16) u16 Ks[2][64 * 64];   // 2x8KB
  __shared__ __align__(16) u16 Vs[2][64 * 64];   // 2x8KB
  const int tid = threadIdx.x, lane = tid & 63, wave = tid >> 6;
  const int l15 = lane & 15, quad = lane >> 4;
  const int sw = l15 & 7;                        // row-swizzle key
  const int bh = blockIdx.x & 63;
  const int b = bh >> 3, h = bh & 7;
  const int t0 = (blockIdx.x >> 6) * 256;
  const u16* qbase = qkv + (long)b * 2048 * 1536 + h * 192;
  const u16* vbase = vt + (long)(b * 8 + h) * 64 * 2048;

  // Q fragments straight from global (A-layout: 16B/lane); wave owns 32 rows
  short8 qf[2][2];
  #pragma unroll
  for (int tqi = 0; tqi < 2; tqi++)
    #pragma unroll
    for (int ks = 0; ks < 2; ks++)
      qf[tqi][ks] = ld8(qbase + (long)(t0 + wave * 32 + tqi * 16 + l15) * 1536 + ks * 32 + quad * 8);

  // ones A-fragment for l-sum MFMA (bf16 1.0 = 0x3F80)
  short8 ones;
  #pragma unroll
  for (int j = 0; j < 8; j++) ones[j] = (short)0x3F80;

  // staging: 512 threads cover the 512 16B chunks of a 64x64 tile.
  // thread covers phys chunk p=tid, reads logical chunk c = (p&7)^(row&7)
  const int prow = tid >> 3, pc = (tid & 7) ^ (prow & 7);
  const u16* kg = qbase + (long)prow * 1536 + 64 + pc * 8;
  const u16* vg = vbase + (long)prow * 2048 + pc * 8;
  const int ldso = wave * 512;                   // wave-uniform base (u16 units)
  async_ld16(kg, &Ks[0][ldso]);
  async_ld16(vg, &Vs[0][ldso]);

  floatx4 accO[4][2];   // [ci][tqi]: row=c, col=tq
  floatx4 lacc[2];      // [tqi]
  #pragma unroll
  for (int ci = 0; ci < 4; ci++)
    #pragma unroll
    for (int tqi = 0; tqi < 2; tqi++) accO[ci][tqi] = (floatx4){0.f, 0.f, 0.f, 0.f};
  #pragma unroll
  for (int tqi = 0; tqi < 2; tqi++) lacc[tqi] = (floatx4){0.f, 0.f, 0.f, 0.f};

  for (int it = 0; it < 32; it++) {
    const u16* kb = Ks[it & 1];
    const u16* vb = Vs[it & 1];
    __syncthreads();                     // publishes tile it; frees buffer it^1
    if (it < 31) {                       // prefetch tile it+1
      int s1 = (it + 1) * 64;
      async_ld16(kg + (long)s1 * 1536, &Ks[(it & 1) ^ 1][ldso]);
      async_ld16(vg + s1,              &Vs[(it & 1) ^ 1][ldso]);
    }

    // S^T[tk][tq] = sum_c K[tk][c] * Q[tq][c]
    floatx4 sacc[4][2];   // [tki][tqi]
    #pragma unroll
    for (int i = 0; i < 4; i++)
      #pragma unroll
      for (int j = 0; j < 2; j++) sacc[i][j] = (floatx4){0.f, 0.f, 0.f, 0.f};
    #pragma unroll
    for (int ks = 0; ks < 2; ks++) {
      short8 kf[4];
      #pragma unroll
      for (int tki = 0; tki < 4; tki++)
        kf[tki] = ld8(&kb[((tki * 16 + l15) << 6) + (((ks * 4 + quad) ^ sw) << 3)]);
      #pragma unroll
      for (int tki = 0; tki < 4; tki++)
        #pragma unroll
        for (int tqi = 0; tqi < 2; tqi++)
          sacc[tki][tqi] = __builtin_amdgcn_mfma_f32_16x16x32_bf16(kf[tki], qf[tqi][ks], sacc[tki][tqi], 0, 0, 0);
    }

    // p = exp2(s) in place (no max-sub; bounded domain)
    #pragma unroll
    for (int tki = 0; tki < 4; tki++)
      #pragma unroll
      for (int tqi = 0; tqi < 2; tqi++)
        #pragma unroll
        for (int r = 0; r < 4; r++)
          sacc[tki][tqi][r] = __builtin_amdgcn_exp2f(sacc[tki][tqi][r]);

    // O^T[c][tq] += sum_tk V^T[c][tk] * P[tq][tk]; l[tq] += sum_tk P
    #pragma unroll
    for (int ks = 0; ks < 2; ks++) {
      short8 vf[4], pf[2];
      #pragma unroll
      for (int ci = 0; ci < 4; ci++)
        vf[ci] = ld8(&vb[((ci * 16 + l15) << 6) + (((ks * 4 + quad) ^ sw) << 3)]);
      #pragma unroll
      for (int tqi = 0; tqi < 2; tqi++) {
        // pack to bf16 words: lo = even-tk, hi = odd-tk (truncation, as before)
        u32 a0 = __builtin_amdgcn_perm(__float_as_uint(sacc[2 * ks][tqi][1]),
                                       __float_as_uint(sacc[2 * ks][tqi][0]), 0x07060302);
        u32 a1 = __builtin_amdgcn_perm(__float_as_uint(sacc[2 * ks][tqi][3]),
                                       __float_as_uint(sacc[2 * ks][tqi][2]), 0x07060302);
        u32 b0 = __builtin_amdgcn_perm(__float_as_uint(sacc[2 * ks + 1][tqi][1]),
                                       __float_as_uint(sacc[2 * ks + 1][tqi][0]), 0x07060302);
        u32 b1 = __builtin_amdgcn_perm(__float_as_uint(sacc[2 * ks + 1][tqi][3]),
                                       __float_as_uint(sacc[2 * ks + 1][tqi][2]), 0x07060302);
        auto u0 = __builtin_amdgcn_permlane32_swap(a0, b0, false, false);
        auto v0 = __builtin_amdgcn_permlane16_swap(u0[0], u0[1], false, false); // w0, w2
        auto u1 = __builtin_amdgcn_permlane32_swap(a1, b1, false, false);
        auto v1 = __builtin_amdgcn_permlane16_swap(u1[0], u1[1], false, false); // w1, w3
        union { u32 w[4]; short8 s8; } pw;
        pw.w[0] = v0[0]; pw.w[1] = v1[0]; pw.w[2] = v0[1]; pw.w[3] = v1[1];
        pf[tqi] = pw.s8;
      }
      #pragma unroll
      for (int tqi = 0; tqi < 2; tqi++)
        lacc[tqi] = __builtin_amdgcn_mfma_f32_16x16x32_bf16(ones, pf[tqi], lacc[tqi], 0, 0, 0);
      #pragma unroll
      for (int ci = 0; ci < 4; ci++)
        #pragma unroll
        for (int tqi = 0; tqi < 2; tqi++)
          accO[ci][tqi] = __builtin_amdgcn_mfma_f32_16x16x32_bf16(vf[ci], pf[tqi], accO[ci][tqi], 0, 0, 0);
    }
  }

  // epilogue: normalize, write a (B,T,C) bf16; lane holds 4 consecutive c
  u16* ob = aout + ((long)b * 2048 + t0 + wave * 32) * 512 + h * 64;
  #pragma unroll
  for (int tqi = 0; tqi < 2; tqi++) {
    float invl = 1.f / lacc[tqi][0];
    #pragma unroll
    for (int ci = 0; ci < 4; ci++) {
      union { u16 u[4]; float2 f; } pk;
      #pragma unroll
      for (int r = 0; r < 4; r++) pk.u[r] = f2bf(accO[ci][tqi][r] * invl);
      *reinterpret_cast<float2*>(ob + (long)(tqi * 16 + l15) * 512 + ci * 16 + quad * 4) = pk.f;
    }
  }
}

// ---------- launch ----------
extern "C" void kernel_launch(void* const* d_in, const int* in_sizes, int n_in,
                              void* d_out, int out_size, void* d_ws, size_t ws_size,
                              hipStream_t stream) {
  const float* x   = (const float*)d_in[0];
  const float* g1  = (const float*)d_in[1];
  const float* be1 = (const float*)d_in[2];
  const float* wq  = (const float*)d_in[3];
  const float* bq  = (const float*)d_in[4];
  const float* g2  = (const float*)d_in[5];
  const float* be2 = (const float*)d_in[6];
  const float* wp  = (const float*)d_in[7];
  const float* bp  = (const float*)d_in[8];

  char* ws = (char*)d_ws;
  u16*   xn   = (u16*)ws;                        // 16.8 MB, dead after gemm1
  u16*   a    = (u16*)ws;                        // bf16 attn out, alias xn (disjoint lifetime)
  u16*   qkvb = (u16*)(ws + 33554432);           // 50.3 MB (q/k live, v-holes unused)
  u16*   hn   = (u16*)(ws + 83886080);           // 16.8 MB, gn2 -> gemm2
  u16*   vtb  = hn;                              // alias: Vt lifetime gemm1 -> attn
  u16*   wqb  = (u16*)(ws + 100663296);          // 1.6 MB
  u16*   wpb  = (u16*)(ws + 102236160);          // 0.5 MB

  gncast<<<512, 1024, 0, stream>>>(x, g1, be1, xn, wq, wqb, wp, wpb);
  // qkv[b][t][o] = sum_c xn[b][t][c] * Wq[o][c] + bq[o]  (+ q-scale, v->Vt)
  gemm_tn<1><<<dim3(12, 16, 8), 256, 0, stream>>>(
      xn, (long)2048 * 512, wqb, 0, bq, nullptr, 0, qkvb, (long)2048 * 1536, vtb, 512);
  attn<<<512, 512, 0, stream>>>(qkvb, vtb, a);
  gn_tc<<<256, 1024, 0, stream>>>(a, g2, be2, hn);
  // out[b][o][t] = x[b][o][t] + bp[o] + sum_c Wp[o][c] * hn[b][t][c]
  gemm_tn<0><<<dim3(16, 4, 8), 256, 0, stream>>>(
      wpb, 0, hn, (long)2048 * 512, bp, x, (long)512 * 2048, d_out, (long)512 * 2048, nullptr, 512);
}